// Round 6
// baseline (557.401 us; speedup 1.0000x reference)
//
#include <hip/hip_runtime.h>
#include <math.h>

#define KC2 128
#define KCH 32   // 4096 / KC2

struct __attribute__((packed)) f4u { float v[4]; };  // 4B-aligned 4-float load

// ---------------- per-pixel channel sum-of-squares ----------------
__global__ __launch_bounds__(256) void sumsq_k(const float* __restrict__ lq,
                                               const float* __restrict__ refdu,
                                               float* __restrict__ S) {
  const float* src = blockIdx.z ? refdu : lq;
  const int n = blockIdx.y;
  const int h = blockIdx.x * 4 + (threadIdx.x >> 6);
  const int w = threadIdx.x & 63;
  const float* p = src + (size_t)n * 1048576 + h * 64 + w;
  float s0 = 0.f, s1 = 0.f, s2 = 0.f, s3 = 0.f;
  #pragma unroll 4
  for (int c = 0; c < 256; c += 4) {
    float x0 = p[(size_t)c * 4096];
    float x1 = p[(size_t)(c + 1) * 4096];
    float x2 = p[(size_t)(c + 2) * 4096];
    float x3 = p[(size_t)(c + 3) * 4096];
    s0 = fmaf(x0, x0, s0); s1 = fmaf(x1, x1, s1);
    s2 = fmaf(x2, x2, s2); s3 = fmaf(x3, x3, s3);
  }
  S[(blockIdx.z * 2 + n) * 4096 + h * 64 + w] = (s0 + s1) + (s2 + s3);
}

// ---------------- 3x3 box-sum -> inverse patch norms ----------------
__global__ __launch_bounds__(256) void norm_k(const float* __restrict__ S,
                                              float* __restrict__ qinv,
                                              float* __restrict__ kinv) {
  int idx = blockIdx.x * 256 + threadIdx.x;   // 0..16383
  int pix = idx & 4095;
  int nn  = (idx >> 12) & 1;
  int arr = idx >> 13;
  int ph = pix >> 6, pw = pix & 63;
  const float* Sp = S + (arr * 2 + nn) * 4096;
  float sum = 0.f;
  #pragma unroll
  for (int dy = -1; dy <= 1; ++dy) {
    int hh = ph + dy;
    if ((unsigned)hh < 64u) {
      const float* r = Sp + hh * 64;
      #pragma unroll
      for (int dx = -1; dx <= 1; ++dx) {
        int ww = pw + dx;
        if ((unsigned)ww < 64u) sum += r[ww];
      }
    }
  }
  float inv = 1.0f / fmaxf(sqrtf(sum), 1e-12f);
  if (arr) kinv[nn * 4096 + pix] = inv;
  else     qinv[nn * 4096 + pix] = inv;
}

// ---------------- f32 GEMM: D[k][j] = sum_c Ref[c][k] * LQ[c][C0+j] ----------------
__global__ __launch_bounds__(256) void gemm_d(const float* __restrict__ Abase,
                                              const float* __restrict__ Bbase,
                                              float* __restrict__ Dbase,
                                              int ldD, int C0, long long dstride) {
  __shared__ __align__(16) float As[2][8][128];
  __shared__ __align__(16) float Bs[2][8][128];
  const int tid = threadIdx.x;
  const int nz = blockIdx.z;
  const int k0 = blockIdx.x * 128;
  const int j0 = blockIdx.y * 128;
  const float* A = Abase + (size_t)nz * 1048576;
  const float* B = Bbase + (size_t)nz * 1048576;
  float* D = Dbase + (size_t)nz * dstride;

  const int ty = tid >> 4;
  const int tx = tid & 15;
  const int lr = tid >> 5;
  const int lc = (tid & 31) << 2;

  float acc[8][8];
  #pragma unroll
  for (int i = 0; i < 8; ++i)
    #pragma unroll
    for (int j = 0; j < 8; ++j) acc[i][j] = 0.f;

  const bool oob = (C0 + j0 < 0) || (C0 + j0 + 128 > 4096);

  if (!oob) {
    const float* Ap = A + k0 + lc;
    const float* Bp = B + (C0 + j0) + lc;

    float4 av = *reinterpret_cast<const float4*>(Ap + (size_t)lr * 4096);
    float4 bv = *reinterpret_cast<const float4*>(Bp + (size_t)lr * 4096);
    *reinterpret_cast<float4*>(&As[0][lr][lc]) = av;
    *reinterpret_cast<float4*>(&Bs[0][lr][lc]) = bv;

    for (int ct = 0; ct < 256; ct += 8) {
      const int buf = (ct >> 3) & 1;
      __syncthreads();
      if (ct + 8 < 256) {
        av = *reinterpret_cast<const float4*>(Ap + (size_t)(ct + 8 + lr) * 4096);
        bv = *reinterpret_cast<const float4*>(Bp + (size_t)(ct + 8 + lr) * 4096);
      }
      #pragma unroll
      for (int kc = 0; kc < 8; ++kc) {
        float a[8], b[8];
        *reinterpret_cast<float4*>(&a[0]) = *reinterpret_cast<const float4*>(&As[buf][kc][ty * 4]);
        *reinterpret_cast<float4*>(&a[4]) = *reinterpret_cast<const float4*>(&As[buf][kc][64 + ty * 4]);
        *reinterpret_cast<float4*>(&b[0]) = *reinterpret_cast<const float4*>(&Bs[buf][kc][tx * 4]);
        *reinterpret_cast<float4*>(&b[4]) = *reinterpret_cast<const float4*>(&Bs[buf][kc][64 + tx * 4]);
        #pragma unroll
        for (int i = 0; i < 8; ++i)
          #pragma unroll
          for (int j = 0; j < 8; ++j)
            acc[i][j] = fmaf(a[i], b[j], acc[i][j]);
      }
      if (ct + 8 < 256) {
        *reinterpret_cast<float4*>(&As[buf ^ 1][lr][lc]) = av;
        *reinterpret_cast<float4*>(&Bs[buf ^ 1][lr][lc]) = bv;
      }
    }
  }

  #pragma unroll
  for (int half = 0; half < 2; ++half) {
    #pragma unroll
    for (int i = 0; i < 4; ++i) {
      float* Dp = D + (size_t)(k0 + half * 64 + ty * 4 + i) * ldD + j0;
      *reinterpret_cast<float4*>(Dp + tx * 4)      = *reinterpret_cast<const float4*>(&acc[half * 4 + i][0]);
      *reinterpret_cast<float4*>(Dp + 64 + tx * 4) = *reinterpret_cast<const float4*>(&acc[half * 4 + i][4]);
    }
  }
}

// ---------------- 9-tap DIAGONAL sum + max/argmax, 4 q per thread ----------------
__global__ __launch_bounds__(256) void reduce_max4(const float* __restrict__ Dbase,
                                                   int ldD, int C0, int Q0,
                                                   const float* __restrict__ kinv,
                                                   float* __restrict__ chunkv,
                                                   int* __restrict__ chunki,
                                                   int n0, long long dstride) {
  __shared__ float sk[KCH];
  const int n = n0 + blockIdx.z;
  const float* D = Dbase + (size_t)blockIdx.z * (size_t)dstride;
  const int k0 = blockIdx.y * KCH;
  const int kh = k0 >> 6;
  const int kwb = k0 & 63;            // 0 or 32
  if (threadIdx.x < KCH) sk[threadIdx.x] = kinv[n * 4096 + k0 + threadIdx.x];
  __syncthreads();

  const int q0 = Q0 + (blockIdx.x * 256 + threadIdx.x) * 4;
  const int qh = q0 >> 6;
  const int qw0 = q0 & 63;
  const bool up = (kh > 0) && (qh > 0);
  const bool dn = (kh < 63) && (qh < 63);
  const bool lf_ok = qw0 > 0;
  const bool rt_ok = qw0 < 60;

  float b0 = -INFINITY, b1 = -INFINITY, b2 = -INFINITY, b3 = -INFINITY;
  int i0 = k0, i1 = k0, i2 = k0, i3 = k0;
  const float* Dq = D + (q0 - C0);
  const int step = ldD + 1;

  #pragma unroll 4
  for (int kk = 0; kk < KCH; ++kk) {
    const int kw = kwb + kk;
    const float* P = Dq + (size_t)(k0 + kk) * ldD;
    float4 c0 = *reinterpret_cast<const float4*>(P);
    float r0 = c0.x, r1 = c0.y, r2 = c0.z, r3 = c0.w;
    if (up) {
      float4 c = *reinterpret_cast<const float4*>(P - 64 * step);
      r0 += c.x; r1 += c.y; r2 += c.z; r3 += c.w;
    }
    if (dn) {
      float4 c = *reinterpret_cast<const float4*>(P + 64 * step);
      r0 += c.x; r1 += c.y; r2 += c.z; r3 += c.w;
    }
    if (kw > 0) {
      f4u a = *reinterpret_cast<const f4u*>(P - step);
      r0 += lf_ok ? a.v[0] : 0.f; r1 += a.v[1]; r2 += a.v[2]; r3 += a.v[3];
      if (up) {
        f4u b = *reinterpret_cast<const f4u*>(P - 65 * step);
        r0 += lf_ok ? b.v[0] : 0.f; r1 += b.v[1]; r2 += b.v[2]; r3 += b.v[3];
      }
      if (dn) {
        f4u b = *reinterpret_cast<const f4u*>(P + 63 * step);
        r0 += lf_ok ? b.v[0] : 0.f; r1 += b.v[1]; r2 += b.v[2]; r3 += b.v[3];
      }
    }
    if (kw < 63) {
      f4u a = *reinterpret_cast<const f4u*>(P + step);
      r0 += a.v[0]; r1 += a.v[1]; r2 += a.v[2]; r3 += rt_ok ? a.v[3] : 0.f;
      if (up) {
        f4u b = *reinterpret_cast<const f4u*>(P - 63 * step);
        r0 += b.v[0]; r1 += b.v[1]; r2 += b.v[2]; r3 += rt_ok ? b.v[3] : 0.f;
      }
      if (dn) {
        f4u b = *reinterpret_cast<const f4u*>(P + 65 * step);
        r0 += b.v[0]; r1 += b.v[1]; r2 += b.v[2]; r3 += rt_ok ? b.v[3] : 0.f;
      }
    }
    const float s = sk[kk];
    const int k = k0 + kk;
    float v0 = r0 * s, v1 = r1 * s, v2 = r2 * s, v3 = r3 * s;
    if (v0 > b0) { b0 = v0; i0 = k; }
    if (v1 > b1) { b1 = v1; i1 = k; }
    if (v2 > b2) { b2 = v2; i2 = k; }
    if (v3 > b3) { b3 = v3; i3 = k; }
  }
  const int ob = (n * KC2 + blockIdx.y) * 4096 + q0;
  *reinterpret_cast<float4*>(chunkv + ob) = make_float4(b0, b1, b2, b3);
  *reinterpret_cast<int4*>(chunki + ob) = make_int4(i0, i1, i2, i3);
}

// ---------------- combine chunks ----------------
__global__ __launch_bounds__(256) void combine_k(const float* __restrict__ chunkv,
                                                 const int* __restrict__ chunki,
                                                 const float* __restrict__ qinv,
                                                 float* __restrict__ out_sa,
                                                 int* __restrict__ maxidx) {
  int t = blockIdx.x * 256 + threadIdx.x;   // 0..8191
  int n = t >> 12, q = t & 4095;
  float best = -INFINITY;
  int bi = 0;
  #pragma unroll 8
  for (int ch = 0; ch < KC2; ++ch) {
    int ii = (n * KC2 + ch) * 4096 + q;
    float v = chunkv[ii];
    int ix = chunki[ii];
    if (v > best) { best = v; bi = ix; }
  }
  maxidx[t] = bi;
  out_sa[t] = best * qinv[t];
}

// ---------------- textures: precomputed tap offsets, c-chunked ----------------
// level 0: s=1, C=256, 64x64. Thread = (n, cc of 8 ch, y, x). 9 scalar taps.
__global__ __launch_bounds__(256) void tex0_k(const float* __restrict__ ref,
                                              const int* __restrict__ maxidx,
                                              float* __restrict__ outp) {
  int gid = blockIdx.x * 256 + threadIdx.x;   // 2*32*64*64 = 262144
  const int x  = gid & 63;
  const int y  = (gid >> 6) & 63;
  const int cc = (gid >> 12) & 31;
  const int n  = gid >> 17;
  const int* mi = maxidx + n * 4096;

  int offs[9];
  #pragma unroll
  for (int a = -1; a <= 1; ++a) {
    #pragma unroll
    for (int b = -1; b <= 1; ++b) {
      const int t = (a + 1) * 3 + (b + 1);
      int jh = y + a, jw = x + b;
      int off = -1;
      if ((unsigned)jh < 64u && (unsigned)jw < 64u) {
        int m = mi[jh * 64 + jw];
        int rh = (m >> 6) - a;        // = sy
        int cx = (m & 63) - b;        // = sx
        if ((unsigned)rh < 64u && (unsigned)cx < 64u) off = rh * 64 + cx;
      }
      offs[t] = off;
    }
  }
  const float* rb = ref + (((size_t)n * 256 + cc * 8) << 12);
  float* ob = outp + (((size_t)n * 256 + cc * 8) << 12) + y * 64 + x;
  #pragma unroll
  for (int i = 0; i < 8; ++i) {
    const float* r = rb + ((size_t)i << 12);
    float acc = 0.f;
    #pragma unroll
    for (int t = 0; t < 9; ++t)
      if (offs[t] >= 0) acc += r[offs[t]];
    ob[(size_t)i << 12] = acc * (1.0f / 9.0f);
  }
}

// level 1: s=2, C=128, 128x128. Thread = (n, cc of 8 ch, y, xg of 4 x). float2 taps.
__global__ __launch_bounds__(256) void tex1_k(const float* __restrict__ ref,
                                              const int* __restrict__ maxidx,
                                              float* __restrict__ outp) {
  int gid = blockIdx.x * 256 + threadIdx.x;   // 2*16*128*32 = 131072
  const int xg = gid & 31;
  const int y  = (gid >> 5) & 127;
  const int cc = (gid >> 12) & 15;
  const int n  = gid >> 16;
  const int jh0 = y >> 1;
  const int* mi = maxidx + n * 4096;

  int offs[2][9];
  #pragma unroll
  for (int h = 0; h < 2; ++h) {
    const int X = 2 * xg + h;
    #pragma unroll
    for (int a = -1; a <= 1; ++a) {
      #pragma unroll
      for (int b = -1; b <= 1; ++b) {
        const int t = (a + 1) * 3 + (b + 1);
        int jh = jh0 + a, jw = X + b;
        int off = -1;
        if ((unsigned)jh < 64u && (unsigned)jw < 64u) {
          int m = mi[jh * 64 + jw];
          int rh = (m >> 6) - jh + jh0;
          int cx = (m & 63) - jw + X;
          if ((unsigned)rh < 64u && (unsigned)cx < 64u)
            off = ((rh << 1) + (y & 1)) * 128 + (cx << 1);
        }
        offs[h][t] = off;
      }
    }
  }
  const float* rb = ref + (((size_t)n * 128 + cc * 8) << 14);
  float* ob = outp + ((((size_t)n * 128 + cc * 8) * 128 + y) << 7) + xg * 4;
  #pragma unroll
  for (int i = 0; i < 8; ++i) {
    const float* r = rb + ((size_t)i << 14);
    float4 acc = make_float4(0.f, 0.f, 0.f, 0.f);
    #pragma unroll
    for (int t = 0; t < 9; ++t) {
      if (offs[0][t] >= 0) {
        float2 v = *reinterpret_cast<const float2*>(r + offs[0][t]);
        acc.x += v.x; acc.y += v.y;
      }
      if (offs[1][t] >= 0) {
        float2 v = *reinterpret_cast<const float2*>(r + offs[1][t]);
        acc.z += v.x; acc.w += v.y;
      }
    }
    acc.x *= (1.f / 9.f); acc.y *= (1.f / 9.f); acc.z *= (1.f / 9.f); acc.w *= (1.f / 9.f);
    *reinterpret_cast<float4*>(ob + ((size_t)i << 14)) = acc;
  }
}

// level 2: s=4, C=64, 256x256. Thread = (n, cc of 8 ch, y, xg of 4 x). float4 taps.
__global__ __launch_bounds__(256) void tex2_k(const float* __restrict__ ref,
                                              const int* __restrict__ maxidx,
                                              float* __restrict__ outp) {
  int gid = blockIdx.x * 256 + threadIdx.x;   // 2*8*256*64 = 262144
  const int xg = gid & 63;
  const int y  = (gid >> 6) & 255;
  const int cc = (gid >> 14) & 7;
  const int n  = gid >> 17;
  const int jh0 = y >> 2;
  const int* mi = maxidx + n * 4096;

  int offs[9];
  #pragma unroll
  for (int a = -1; a <= 1; ++a) {
    #pragma unroll
    for (int b = -1; b <= 1; ++b) {
      const int t = (a + 1) * 3 + (b + 1);
      int jh = jh0 + a, jw = xg + b;
      int off = -1;
      if ((unsigned)jh < 64u && (unsigned)jw < 64u) {
        int m = mi[jh * 64 + jw];
        int rh = (m >> 6) - jh + jh0;
        int cx = (m & 63) - jw + xg;
        if ((unsigned)rh < 64u && (unsigned)cx < 64u)
          off = ((rh << 2) + (y & 3)) * 256 + (cx << 2);
      }
      offs[t] = off;
    }
  }
  const float* rb = ref + (((size_t)n * 64 + cc * 8) << 16);
  float* ob = outp + ((((size_t)n * 64 + cc * 8) * 256 + y) << 8) + xg * 4;
  #pragma unroll
  for (int i = 0; i < 8; ++i) {
    const float* r = rb + ((size_t)i << 16);
    float4 acc = make_float4(0.f, 0.f, 0.f, 0.f);
    #pragma unroll
    for (int t = 0; t < 9; ++t) {
      if (offs[t] >= 0) {
        float4 v = *reinterpret_cast<const float4*>(r + offs[t]);
        acc.x += v.x; acc.y += v.y; acc.z += v.z; acc.w += v.w;
      }
    }
    acc.x *= (1.f / 9.f); acc.y *= (1.f / 9.f); acc.z *= (1.f / 9.f); acc.w *= (1.f / 9.f);
    *reinterpret_cast<float4*>(ob + ((size_t)i << 16)) = acc;
  }
}

// ---------------- launch ----------------
extern "C" void kernel_launch(void* const* d_in, const int* in_sizes, int n_in,
                              void* d_out, int out_size, void* d_ws, size_t ws_size,
                              hipStream_t stream) {
  const float* lq    = (const float*)d_in[0];
  const float* refdu = (const float*)d_in[1];
  const float* ref0  = (const float*)d_in[2];
  const float* ref1  = (const float*)d_in[3];
  const float* ref2  = (const float*)d_in[4];
  float* out = (float*)d_out;

  float* S      = (float*)d_ws;               // 16384
  float* qinv   = S + 16384;                  // 8192
  float* kinv   = qinv + 8192;                // 8192
  int*   maxidx = (int*)(kinv + 8192);        // 8192
  float* chunkv = (float*)(maxidx + 8192);    // 2*KC2*4096 = 1048576
  int*   chunki = (int*)(chunkv + 1048576);   // 1048576
  const size_t aux_bytes = (size_t)(16384 + 8192 + 8192 + 8192 + 1048576 + 1048576) * 4;
  float* D = (float*)((char*)d_ws + aux_bytes);

  size_t avail = (ws_size > aux_bytes) ? (ws_size - aux_bytes) : 0;
  const size_t stripe4096 = (size_t)4096 * 4352 * 4;

  sumsq_k<<<dim3(16, 2, 2), 256, 0, stream>>>(lq, refdu, S);
  norm_k<<<dim3(64), 256, 0, stream>>>(S, qinv, kinv);

  if (avail >= 2 * stripe4096) {
    const int ldD = 4352, C0 = -128;
    const long long dstride = (long long)4096 * 4352;
    gemm_d<<<dim3(32, ldD / 128, 2), 256, 0, stream>>>(refdu, lq, D, ldD, C0, dstride);
    reduce_max4<<<dim3(4, KC2, 2), 256, 0, stream>>>(D, ldD, C0, 0, kinv,
                                                     chunkv, chunki, 0, dstride);
  } else {
    int Wq = 1024;
    const int cands[3] = {4096, 2048, 1024};
    for (int i = 0; i < 3; ++i) {
      size_t need = (size_t)4096 * (size_t)(cands[i] + 256) * 4;
      if (need <= avail) { Wq = cands[i]; break; }
    }
    const int ldD = Wq + 256;
    for (int n = 0; n < 2; ++n) {
      const float* A = refdu + (size_t)n * 1048576;
      const float* B = lq    + (size_t)n * 1048576;
      for (int Q0 = 0; Q0 < 4096; Q0 += Wq) {
        int C0 = Q0 - 128;
        gemm_d<<<dim3(32, ldD / 128, 1), 256, 0, stream>>>(A, B, D, ldD, C0, 0);
        reduce_max4<<<dim3(Wq / 1024, KC2, 1), 256, 0, stream>>>(
            D, ldD, C0, Q0, kinv, chunkv, chunki, n, 0);
      }
    }
  }

  combine_k<<<dim3(32), 256, 0, stream>>>(chunkv, chunki, qinv, out, maxidx);

  tex0_k<<<dim3(1024), 256, 0, stream>>>(ref0, maxidx, out + 8192);
  tex1_k<<<dim3(512),  256, 0, stream>>>(ref1, maxidx, out + 2105344);
  tex2_k<<<dim3(1024), 256, 0, stream>>>(ref2, maxidx, out + 6299648);
}

// Round 7
// 556.831 us; speedup vs baseline: 1.0010x; 1.0010x over previous
//
#include <hip/hip_runtime.h>
#include <math.h>

#define KC2 128
#define KCH 32   // 4096 / KC2

struct __attribute__((packed)) f4u { float v[4]; };  // 4B-aligned 4-float load

// ---------------- per-pixel channel sum-of-squares ----------------
__global__ __launch_bounds__(256) void sumsq_k(const float* __restrict__ lq,
                                               const float* __restrict__ refdu,
                                               float* __restrict__ S) {
  const float* src = blockIdx.z ? refdu : lq;
  const int n = blockIdx.y;
  const int h = blockIdx.x * 4 + (threadIdx.x >> 6);
  const int w = threadIdx.x & 63;
  const float* p = src + (size_t)n * 1048576 + h * 64 + w;
  float s0 = 0.f, s1 = 0.f, s2 = 0.f, s3 = 0.f;
  #pragma unroll 4
  for (int c = 0; c < 256; c += 4) {
    float x0 = p[(size_t)c * 4096];
    float x1 = p[(size_t)(c + 1) * 4096];
    float x2 = p[(size_t)(c + 2) * 4096];
    float x3 = p[(size_t)(c + 3) * 4096];
    s0 = fmaf(x0, x0, s0); s1 = fmaf(x1, x1, s1);
    s2 = fmaf(x2, x2, s2); s3 = fmaf(x3, x3, s3);
  }
  S[(blockIdx.z * 2 + n) * 4096 + h * 64 + w] = (s0 + s1) + (s2 + s3);
}

// ---------------- 3x3 box-sum -> inverse patch norms ----------------
__global__ __launch_bounds__(256) void norm_k(const float* __restrict__ S,
                                              float* __restrict__ qinv,
                                              float* __restrict__ kinv) {
  int idx = blockIdx.x * 256 + threadIdx.x;   // 0..16383
  int pix = idx & 4095;
  int nn  = (idx >> 12) & 1;
  int arr = idx >> 13;
  int ph = pix >> 6, pw = pix & 63;
  const float* Sp = S + (arr * 2 + nn) * 4096;
  float sum = 0.f;
  #pragma unroll
  for (int dy = -1; dy <= 1; ++dy) {
    int hh = ph + dy;
    if ((unsigned)hh < 64u) {
      const float* r = Sp + hh * 64;
      #pragma unroll
      for (int dx = -1; dx <= 1; ++dx) {
        int ww = pw + dx;
        if ((unsigned)ww < 64u) sum += r[ww];
      }
    }
  }
  float inv = 1.0f / fmaxf(sqrtf(sum), 1e-12f);
  if (arr) kinv[nn * 4096 + pix] = inv;
  else     qinv[nn * 4096 + pix] = inv;
}

// ---------------- f32 GEMM: D[k][j] = sum_c Ref[c][k] * LQ[c][C0+j] ----------------
// grid: (4096/256, ldD/128, nz); block 256; 256x128 tile, 16x8/thread;
// double-buffered LDS, 1 barrier per K-step; conflict-free LDS.
__global__ __launch_bounds__(256) void gemm_d(const float* __restrict__ Abase,
                                              const float* __restrict__ Bbase,
                                              float* __restrict__ Dbase,
                                              int ldD, int C0, long long dstride) {
  __shared__ __align__(16) float As[2][8][256];
  __shared__ __align__(16) float Bs[2][8][128];
  const int tid = threadIdx.x;
  const int nz = blockIdx.z;
  const int k0 = blockIdx.x * 256;
  const int j0 = blockIdx.y * 128;
  const float* A = Abase + (size_t)nz * 1048576;
  const float* B = Bbase + (size_t)nz * 1048576;
  float* D = Dbase + (size_t)nz * dstride;

  const int ty = tid >> 4;            // 0..15 -> a rows {q*64 + ty*4}
  const int tx = tid & 15;            // 0..15 -> b cols {tx*4, 64+tx*4}
  const int ar0 = tid >> 6;           // A staging row 0..3 (and +4)
  const int ac0 = (tid & 63) << 2;    // A staging col
  const int br  = tid >> 5;           // B staging row 0..7
  const int bc  = (tid & 31) << 2;    // B staging col

  float acc[16][8];
  #pragma unroll
  for (int i = 0; i < 16; ++i)
    #pragma unroll
    for (int j = 0; j < 8; ++j) acc[i][j] = 0.f;

  const bool oob = (C0 + j0 < 0) || (C0 + j0 + 128 > 4096);

  if (!oob) {
    const float* Ap = A + k0;
    const float* Bp = B + (C0 + j0);

    float4 av0 = *reinterpret_cast<const float4*>(Ap + (size_t)ar0 * 4096 + ac0);
    float4 av1 = *reinterpret_cast<const float4*>(Ap + (size_t)(ar0 + 4) * 4096 + ac0);
    float4 bv  = *reinterpret_cast<const float4*>(Bp + (size_t)br * 4096 + bc);
    *reinterpret_cast<float4*>(&As[0][ar0][ac0])     = av0;
    *reinterpret_cast<float4*>(&As[0][ar0 + 4][ac0]) = av1;
    *reinterpret_cast<float4*>(&Bs[0][br][bc])       = bv;

    for (int ct = 0; ct < 256; ct += 8) {
      const int buf = (ct >> 3) & 1;
      __syncthreads();
      if (ct + 8 < 256) {
        av0 = *reinterpret_cast<const float4*>(Ap + (size_t)(ct + 8 + ar0) * 4096 + ac0);
        av1 = *reinterpret_cast<const float4*>(Ap + (size_t)(ct + 12 + ar0) * 4096 + ac0);
        bv  = *reinterpret_cast<const float4*>(Bp + (size_t)(ct + 8 + br) * 4096 + bc);
      }
      #pragma unroll
      for (int kc = 0; kc < 8; ++kc) {
        float a[16], b[8];
        #pragma unroll
        for (int q = 0; q < 4; ++q)
          *reinterpret_cast<float4*>(&a[q * 4]) =
              *reinterpret_cast<const float4*>(&As[buf][kc][q * 64 + ty * 4]);
        *reinterpret_cast<float4*>(&b[0]) = *reinterpret_cast<const float4*>(&Bs[buf][kc][tx * 4]);
        *reinterpret_cast<float4*>(&b[4]) = *reinterpret_cast<const float4*>(&Bs[buf][kc][64 + tx * 4]);
        #pragma unroll
        for (int i = 0; i < 16; ++i)
          #pragma unroll
          for (int j = 0; j < 8; ++j)
            acc[i][j] = fmaf(a[i], b[j], acc[i][j]);
      }
      if (ct + 8 < 256) {
        *reinterpret_cast<float4*>(&As[buf ^ 1][ar0][ac0])     = av0;
        *reinterpret_cast<float4*>(&As[buf ^ 1][ar0 + 4][ac0]) = av1;
        *reinterpret_cast<float4*>(&Bs[buf ^ 1][br][bc])       = bv;
      }
    }
  }

  // epilogue: rows k0 + q*64 + ty*4 + i, cols j0 + {tx*4, 64+tx*4}
  #pragma unroll
  for (int q = 0; q < 4; ++q) {
    #pragma unroll
    for (int i = 0; i < 4; ++i) {
      float* Dp = D + (size_t)(k0 + q * 64 + ty * 4 + i) * ldD + j0;
      *reinterpret_cast<float4*>(Dp + tx * 4)      = *reinterpret_cast<const float4*>(&acc[q * 4 + i][0]);
      *reinterpret_cast<float4*>(Dp + 64 + tx * 4) = *reinterpret_cast<const float4*>(&acc[q * 4 + i][4]);
    }
  }
}

// ---------------- 9-tap DIAGONAL sum + max/argmax, 8 q per thread ----------------
// grid: (Wq/2048, KC2, nz); block 256. Chunk = 32 k within one key row.
__global__ __launch_bounds__(256) void reduce_max8(const float* __restrict__ Dbase,
                                                   int ldD, int C0, int Q0,
                                                   const float* __restrict__ kinv,
                                                   float* __restrict__ chunkv,
                                                   int* __restrict__ chunki,
                                                   int n0, long long dstride) {
  __shared__ float sk[KCH];
  const int n = n0 + blockIdx.z;
  const float* D = Dbase + (size_t)blockIdx.z * (size_t)dstride;
  const int k0 = blockIdx.y * KCH;
  const int kh = k0 >> 6;
  const int kwb = k0 & 63;
  if (threadIdx.x < KCH) sk[threadIdx.x] = kinv[n * 4096 + k0 + threadIdx.x];
  __syncthreads();

  const int q0 = Q0 + (blockIdx.x * 256 + threadIdx.x) * 8;
  const int qh = q0 >> 6;
  const int qw0 = q0 & 63;           // multiple of 8
  const bool up = (kh > 0) && (qh > 0);
  const bool dn = (kh < 63) && (qh < 63);
  const bool lf_ok = qw0 > 0;        // elem 0's dx=-1 tap column valid
  const bool rt_ok = qw0 < 56;       // elem 7's dx=+1 tap column valid

  float best[8];
  int bidx[8];
  #pragma unroll
  for (int i = 0; i < 8; ++i) { best[i] = -INFINITY; bidx[i] = k0; }

  const float* Dq = D + (q0 - C0);
  const int step = ldD + 1;

  #pragma unroll 2
  for (int kk = 0; kk < KCH; ++kk) {
    const int kw = kwb + kk;
    const float* P = Dq + (size_t)(k0 + kk) * ldD;
    float r[8];
    {
      float4 c0 = *reinterpret_cast<const float4*>(P);
      float4 c1 = *reinterpret_cast<const float4*>(P + 4);
      r[0] = c0.x; r[1] = c0.y; r[2] = c0.z; r[3] = c0.w;
      r[4] = c1.x; r[5] = c1.y; r[6] = c1.z; r[7] = c1.w;
    }
    if (up) {
      float4 c0 = *reinterpret_cast<const float4*>(P - 64 * step);
      float4 c1 = *reinterpret_cast<const float4*>(P - 64 * step + 4);
      r[0] += c0.x; r[1] += c0.y; r[2] += c0.z; r[3] += c0.w;
      r[4] += c1.x; r[5] += c1.y; r[6] += c1.z; r[7] += c1.w;
    }
    if (dn) {
      float4 c0 = *reinterpret_cast<const float4*>(P + 64 * step);
      float4 c1 = *reinterpret_cast<const float4*>(P + 64 * step + 4);
      r[0] += c0.x; r[1] += c0.y; r[2] += c0.z; r[3] += c0.w;
      r[4] += c1.x; r[5] += c1.y; r[6] += c1.z; r[7] += c1.w;
    }
    if (kw > 0) {                    // dx = -1 taps; elem 0 masked by lf_ok
      const float* base = P - step;
      f4u a0 = *reinterpret_cast<const f4u*>(base);
      f4u a1 = *reinterpret_cast<const f4u*>(base + 4);
      r[0] += lf_ok ? a0.v[0] : 0.f; r[1] += a0.v[1]; r[2] += a0.v[2]; r[3] += a0.v[3];
      r[4] += a1.v[0]; r[5] += a1.v[1]; r[6] += a1.v[2]; r[7] += a1.v[3];
      if (up) {
        const float* b = P - 65 * step;
        f4u b0 = *reinterpret_cast<const f4u*>(b);
        f4u b1 = *reinterpret_cast<const f4u*>(b + 4);
        r[0] += lf_ok ? b0.v[0] : 0.f; r[1] += b0.v[1]; r[2] += b0.v[2]; r[3] += b0.v[3];
        r[4] += b1.v[0]; r[5] += b1.v[1]; r[6] += b1.v[2]; r[7] += b1.v[3];
      }
      if (dn) {
        const float* b = P + 63 * step;
        f4u b0 = *reinterpret_cast<const f4u*>(b);
        f4u b1 = *reinterpret_cast<const f4u*>(b + 4);
        r[0] += lf_ok ? b0.v[0] : 0.f; r[1] += b0.v[1]; r[2] += b0.v[2]; r[3] += b0.v[3];
        r[4] += b1.v[0]; r[5] += b1.v[1]; r[6] += b1.v[2]; r[7] += b1.v[3];
      }
    }
    if (kw < 63) {                   // dx = +1 taps; elem 7 masked by rt_ok
      const float* base = P + step;
      f4u a0 = *reinterpret_cast<const f4u*>(base);
      f4u a1 = *reinterpret_cast<const f4u*>(base + 4);
      r[0] += a0.v[0]; r[1] += a0.v[1]; r[2] += a0.v[2]; r[3] += a0.v[3];
      r[4] += a1.v[0]; r[5] += a1.v[1]; r[6] += a1.v[2]; r[7] += rt_ok ? a1.v[3] : 0.f;
      if (up) {
        const float* b = P - 63 * step;
        f4u b0 = *reinterpret_cast<const f4u*>(b);
        f4u b1 = *reinterpret_cast<const f4u*>(b + 4);
        r[0] += b0.v[0]; r[1] += b0.v[1]; r[2] += b0.v[2]; r[3] += b0.v[3];
        r[4] += b1.v[0]; r[5] += b1.v[1]; r[6] += b1.v[2]; r[7] += rt_ok ? b1.v[3] : 0.f;
      }
      if (dn) {
        const float* b = P + 65 * step;
        f4u b0 = *reinterpret_cast<const f4u*>(b);
        f4u b1 = *reinterpret_cast<const f4u*>(b + 4);
        r[0] += b0.v[0]; r[1] += b0.v[1]; r[2] += b0.v[2]; r[3] += b0.v[3];
        r[4] += b1.v[0]; r[5] += b1.v[1]; r[6] += b1.v[2]; r[7] += rt_ok ? b1.v[3] : 0.f;
      }
    }
    const float s = sk[kk];
    const int k = k0 + kk;
    #pragma unroll
    for (int i = 0; i < 8; ++i) {
      float v = r[i] * s;
      if (v > best[i]) { best[i] = v; bidx[i] = k; }
    }
  }
  const int ob = (n * KC2 + blockIdx.y) * 4096 + q0;
  *reinterpret_cast<float4*>(chunkv + ob)     = make_float4(best[0], best[1], best[2], best[3]);
  *reinterpret_cast<float4*>(chunkv + ob + 4) = make_float4(best[4], best[5], best[6], best[7]);
  *reinterpret_cast<int4*>(chunki + ob)     = make_int4(bidx[0], bidx[1], bidx[2], bidx[3]);
  *reinterpret_cast<int4*>(chunki + ob + 4) = make_int4(bidx[4], bidx[5], bidx[6], bidx[7]);
}

// ---------------- combine chunks ----------------
__global__ __launch_bounds__(256) void combine_k(const float* __restrict__ chunkv,
                                                 const int* __restrict__ chunki,
                                                 const float* __restrict__ qinv,
                                                 float* __restrict__ out_sa,
                                                 int* __restrict__ maxidx) {
  int t = blockIdx.x * 256 + threadIdx.x;   // 0..8191
  int n = t >> 12, q = t & 4095;
  float best = -INFINITY;
  int bi = 0;
  #pragma unroll 8
  for (int ch = 0; ch < KC2; ++ch) {
    int ii = (n * KC2 + ch) * 4096 + q;
    float v = chunkv[ii];
    int ix = chunki[ii];
    if (v > best) { best = v; bi = ix; }
  }
  maxidx[t] = bi;
  out_sa[t] = best * qinv[t];
}

// ---------------- textures: precomputed tap offsets, c-chunked ----------------
__global__ __launch_bounds__(256) void tex0_k(const float* __restrict__ ref,
                                              const int* __restrict__ maxidx,
                                              float* __restrict__ outp) {
  int gid = blockIdx.x * 256 + threadIdx.x;   // 262144
  const int x  = gid & 63;
  const int y  = (gid >> 6) & 63;
  const int cc = (gid >> 12) & 31;
  const int n  = gid >> 17;
  const int* mi = maxidx + n * 4096;

  int offs[9];
  #pragma unroll
  for (int a = -1; a <= 1; ++a) {
    #pragma unroll
    for (int b = -1; b <= 1; ++b) {
      const int t = (a + 1) * 3 + (b + 1);
      int jh = y + a, jw = x + b;
      int off = -1;
      if ((unsigned)jh < 64u && (unsigned)jw < 64u) {
        int m = mi[jh * 64 + jw];
        int rh = (m >> 6) - a;
        int cx = (m & 63) - b;
        if ((unsigned)rh < 64u && (unsigned)cx < 64u) off = rh * 64 + cx;
      }
      offs[t] = off;
    }
  }
  const float* rb = ref + (((size_t)n * 256 + cc * 8) << 12);
  float* ob = outp + (((size_t)n * 256 + cc * 8) << 12) + y * 64 + x;
  #pragma unroll
  for (int i = 0; i < 8; ++i) {
    const float* r = rb + ((size_t)i << 12);
    float acc = 0.f;
    #pragma unroll
    for (int t = 0; t < 9; ++t)
      if (offs[t] >= 0) acc += r[offs[t]];
    ob[(size_t)i << 12] = acc * (1.0f / 9.0f);
  }
}

__global__ __launch_bounds__(256) void tex1_k(const float* __restrict__ ref,
                                              const int* __restrict__ maxidx,
                                              float* __restrict__ outp) {
  int gid = blockIdx.x * 256 + threadIdx.x;   // 131072
  const int xg = gid & 31;
  const int y  = (gid >> 5) & 127;
  const int cc = (gid >> 12) & 15;
  const int n  = gid >> 16;
  const int jh0 = y >> 1;
  const int* mi = maxidx + n * 4096;

  int offs[2][9];
  #pragma unroll
  for (int h = 0; h < 2; ++h) {
    const int X = 2 * xg + h;
    #pragma unroll
    for (int a = -1; a <= 1; ++a) {
      #pragma unroll
      for (int b = -1; b <= 1; ++b) {
        const int t = (a + 1) * 3 + (b + 1);
        int jh = jh0 + a, jw = X + b;
        int off = -1;
        if ((unsigned)jh < 64u && (unsigned)jw < 64u) {
          int m = mi[jh * 64 + jw];
          int rh = (m >> 6) - jh + jh0;
          int cx = (m & 63) - jw + X;
          if ((unsigned)rh < 64u && (unsigned)cx < 64u)
            off = ((rh << 1) + (y & 1)) * 128 + (cx << 1);
        }
        offs[h][t] = off;
      }
    }
  }
  const float* rb = ref + (((size_t)n * 128 + cc * 8) << 14);
  float* ob = outp + ((((size_t)n * 128 + cc * 8) * 128 + y) << 7) + xg * 4;
  #pragma unroll
  for (int i = 0; i < 8; ++i) {
    const float* r = rb + ((size_t)i << 14);
    float4 acc = make_float4(0.f, 0.f, 0.f, 0.f);
    #pragma unroll
    for (int t = 0; t < 9; ++t) {
      if (offs[0][t] >= 0) {
        float2 v = *reinterpret_cast<const float2*>(r + offs[0][t]);
        acc.x += v.x; acc.y += v.y;
      }
      if (offs[1][t] >= 0) {
        float2 v = *reinterpret_cast<const float2*>(r + offs[1][t]);
        acc.z += v.x; acc.w += v.y;
      }
    }
    acc.x *= (1.f / 9.f); acc.y *= (1.f / 9.f); acc.z *= (1.f / 9.f); acc.w *= (1.f / 9.f);
    *reinterpret_cast<float4*>(ob + ((size_t)i << 14)) = acc;
  }
}

__global__ __launch_bounds__(256) void tex2_k(const float* __restrict__ ref,
                                              const int* __restrict__ maxidx,
                                              float* __restrict__ outp) {
  int gid = blockIdx.x * 256 + threadIdx.x;   // 262144
  const int xg = gid & 63;
  const int y  = (gid >> 6) & 255;
  const int cc = (gid >> 14) & 7;
  const int n  = gid >> 17;
  const int jh0 = y >> 2;
  const int* mi = maxidx + n * 4096;

  int offs[9];
  #pragma unroll
  for (int a = -1; a <= 1; ++a) {
    #pragma unroll
    for (int b = -1; b <= 1; ++b) {
      const int t = (a + 1) * 3 + (b + 1);
      int jh = jh0 + a, jw = xg + b;
      int off = -1;
      if ((unsigned)jh < 64u && (unsigned)jw < 64u) {
        int m = mi[jh * 64 + jw];
        int rh = (m >> 6) - jh + jh0;
        int cx = (m & 63) - jw + xg;
        if ((unsigned)rh < 64u && (unsigned)cx < 64u)
          off = ((rh << 2) + (y & 3)) * 256 + (cx << 2);
      }
      offs[t] = off;
    }
  }
  const float* rb = ref + (((size_t)n * 64 + cc * 8) << 16);
  float* ob = outp + ((((size_t)n * 64 + cc * 8) * 256 + y) << 8) + xg * 4;
  #pragma unroll
  for (int i = 0; i < 8; ++i) {
    const float* r = rb + ((size_t)i << 16);
    float4 acc = make_float4(0.f, 0.f, 0.f, 0.f);
    #pragma unroll
    for (int t = 0; t < 9; ++t) {
      if (offs[t] >= 0) {
        float4 v = *reinterpret_cast<const float4*>(r + offs[t]);
        acc.x += v.x; acc.y += v.y; acc.z += v.z; acc.w += v.w;
      }
    }
    acc.x *= (1.f / 9.f); acc.y *= (1.f / 9.f); acc.z *= (1.f / 9.f); acc.w *= (1.f / 9.f);
    *reinterpret_cast<float4*>(ob + ((size_t)i << 16)) = acc;
  }
}

// ---------------- launch ----------------
extern "C" void kernel_launch(void* const* d_in, const int* in_sizes, int n_in,
                              void* d_out, int out_size, void* d_ws, size_t ws_size,
                              hipStream_t stream) {
  const float* lq    = (const float*)d_in[0];
  const float* refdu = (const float*)d_in[1];
  const float* ref0  = (const float*)d_in[2];
  const float* ref1  = (const float*)d_in[3];
  const float* ref2  = (const float*)d_in[4];
  float* out = (float*)d_out;

  float* S      = (float*)d_ws;               // 16384
  float* qinv   = S + 16384;                  // 8192
  float* kinv   = qinv + 8192;                // 8192
  int*   maxidx = (int*)(kinv + 8192);        // 8192
  float* chunkv = (float*)(maxidx + 8192);    // 2*KC2*4096 = 1048576
  int*   chunki = (int*)(chunkv + 1048576);   // 1048576
  const size_t aux_bytes = (size_t)(16384 + 8192 + 8192 + 8192 + 1048576 + 1048576) * 4;
  float* D = (float*)((char*)d_ws + aux_bytes);

  size_t avail = (ws_size > aux_bytes) ? (ws_size - aux_bytes) : 0;
  const size_t stripe4096 = (size_t)4096 * 4352 * 4;

  sumsq_k<<<dim3(16, 2, 2), 256, 0, stream>>>(lq, refdu, S);
  norm_k<<<dim3(64), 256, 0, stream>>>(S, qinv, kinv);

  if (avail >= 2 * stripe4096) {
    const int ldD = 4352, C0 = -128;
    const long long dstride = (long long)4096 * 4352;
    gemm_d<<<dim3(16, ldD / 128, 2), 256, 0, stream>>>(refdu, lq, D, ldD, C0, dstride);
    reduce_max8<<<dim3(2, KC2, 2), 256, 0, stream>>>(D, ldD, C0, 0, kinv,
                                                     chunkv, chunki, 0, dstride);
  } else {
    // stripe fallback (Wq multiple of 2048)
    int Wq = 2048;
    if ((size_t)4096 * (4096 + 256) * 4 <= avail) Wq = 4096;
    const int ldD = Wq + 256;
    for (int n = 0; n < 2; ++n) {
      const float* A = refdu + (size_t)n * 1048576;
      const float* B = lq    + (size_t)n * 1048576;
      for (int Q0 = 0; Q0 < 4096; Q0 += Wq) {
        int C0 = Q0 - 128;
        gemm_d<<<dim3(16, ldD / 128, 1), 256, 0, stream>>>(A, B, D, ldD, C0, 0);
        reduce_max8<<<dim3(Wq / 2048, KC2, 1), 256, 0, stream>>>(
            D, ldD, C0, Q0, kinv, chunkv, chunki, n, 0);
      }
    }
  }

  combine_k<<<dim3(32), 256, 0, stream>>>(chunkv, chunki, qinv, out, maxidx);

  tex0_k<<<dim3(1024), 256, 0, stream>>>(ref0, maxidx, out + 8192);
  tex1_k<<<dim3(512),  256, 0, stream>>>(ref1, maxidx, out + 2105344);
  tex2_k<<<dim3(1024), 256, 0, stream>>>(ref2, maxidx, out + 6299648);
}

// Round 8
// 487.798 us; speedup vs baseline: 1.1427x; 1.1415x over previous
//
#include <hip/hip_runtime.h>
#include <math.h>

#define KC2 128
#define KCH 32   // 4096 / KC2

struct __attribute__((packed)) f4u { float v[4]; };  // 4B-aligned 4-float load

// ---------------- per-pixel channel sum-of-squares ----------------
__global__ __launch_bounds__(256) void sumsq_k(const float* __restrict__ lq,
                                               const float* __restrict__ refdu,
                                               float* __restrict__ S) {
  const float* src = blockIdx.z ? refdu : lq;
  const int n = blockIdx.y;
  const int h = blockIdx.x * 4 + (threadIdx.x >> 6);
  const int w = threadIdx.x & 63;
  const float* p = src + (size_t)n * 1048576 + h * 64 + w;
  float s0 = 0.f, s1 = 0.f, s2 = 0.f, s3 = 0.f;
  #pragma unroll 4
  for (int c = 0; c < 256; c += 4) {
    float x0 = p[(size_t)c * 4096];
    float x1 = p[(size_t)(c + 1) * 4096];
    float x2 = p[(size_t)(c + 2) * 4096];
    float x3 = p[(size_t)(c + 3) * 4096];
    s0 = fmaf(x0, x0, s0); s1 = fmaf(x1, x1, s1);
    s2 = fmaf(x2, x2, s2); s3 = fmaf(x3, x3, s3);
  }
  S[(blockIdx.z * 2 + n) * 4096 + h * 64 + w] = (s0 + s1) + (s2 + s3);
}

// ---------------- 3x3 box-sum -> inverse patch norms ----------------
__global__ __launch_bounds__(256) void norm_k(const float* __restrict__ S,
                                              float* __restrict__ qinv,
                                              float* __restrict__ kinv) {
  int idx = blockIdx.x * 256 + threadIdx.x;   // 0..16383
  int pix = idx & 4095;
  int nn  = (idx >> 12) & 1;
  int arr = idx >> 13;
  int ph = pix >> 6, pw = pix & 63;
  const float* Sp = S + (arr * 2 + nn) * 4096;
  float sum = 0.f;
  #pragma unroll
  for (int dy = -1; dy <= 1; ++dy) {
    int hh = ph + dy;
    if ((unsigned)hh < 64u) {
      const float* r = Sp + hh * 64;
      #pragma unroll
      for (int dx = -1; dx <= 1; ++dx) {
        int ww = pw + dx;
        if ((unsigned)ww < 64u) sum += r[ww];
      }
    }
  }
  float inv = 1.0f / fmaxf(sqrtf(sum), 1e-12f);
  if (arr) kinv[nn * 4096 + pix] = inv;
  else     qinv[nn * 4096 + pix] = inv;
}

// ---------------- f32 GEMM: D[k][j] = sum_c Ref[c][k] * LQ[c][C0+j] ----------------
// 128x128 tile, 8x8/thread 4+4 split, dbuf LDS (round-5 version; best measured)
__global__ __launch_bounds__(256) void gemm_d(const float* __restrict__ Abase,
                                              const float* __restrict__ Bbase,
                                              float* __restrict__ Dbase,
                                              int ldD, int C0, long long dstride) {
  __shared__ __align__(16) float As[2][8][128];
  __shared__ __align__(16) float Bs[2][8][128];
  const int tid = threadIdx.x;
  const int nz = blockIdx.z;
  const int k0 = blockIdx.x * 128;
  const int j0 = blockIdx.y * 128;
  const float* A = Abase + (size_t)nz * 1048576;
  const float* B = Bbase + (size_t)nz * 1048576;
  float* D = Dbase + (size_t)nz * dstride;

  const int ty = tid >> 4;
  const int tx = tid & 15;
  const int lr = tid >> 5;
  const int lc = (tid & 31) << 2;

  float acc[8][8];
  #pragma unroll
  for (int i = 0; i < 8; ++i)
    #pragma unroll
    for (int j = 0; j < 8; ++j) acc[i][j] = 0.f;

  const bool oob = (C0 + j0 < 0) || (C0 + j0 + 128 > 4096);

  if (!oob) {
    const float* Ap = A + k0 + lc;
    const float* Bp = B + (C0 + j0) + lc;

    float4 av = *reinterpret_cast<const float4*>(Ap + (size_t)lr * 4096);
    float4 bv = *reinterpret_cast<const float4*>(Bp + (size_t)lr * 4096);
    *reinterpret_cast<float4*>(&As[0][lr][lc]) = av;
    *reinterpret_cast<float4*>(&Bs[0][lr][lc]) = bv;

    for (int ct = 0; ct < 256; ct += 8) {
      const int buf = (ct >> 3) & 1;
      __syncthreads();
      if (ct + 8 < 256) {
        av = *reinterpret_cast<const float4*>(Ap + (size_t)(ct + 8 + lr) * 4096);
        bv = *reinterpret_cast<const float4*>(Bp + (size_t)(ct + 8 + lr) * 4096);
      }
      #pragma unroll
      for (int kc = 0; kc < 8; ++kc) {
        float a[8], b[8];
        *reinterpret_cast<float4*>(&a[0]) = *reinterpret_cast<const float4*>(&As[buf][kc][ty * 4]);
        *reinterpret_cast<float4*>(&a[4]) = *reinterpret_cast<const float4*>(&As[buf][kc][64 + ty * 4]);
        *reinterpret_cast<float4*>(&b[0]) = *reinterpret_cast<const float4*>(&Bs[buf][kc][tx * 4]);
        *reinterpret_cast<float4*>(&b[4]) = *reinterpret_cast<const float4*>(&Bs[buf][kc][64 + tx * 4]);
        #pragma unroll
        for (int i = 0; i < 8; ++i)
          #pragma unroll
          for (int j = 0; j < 8; ++j)
            acc[i][j] = fmaf(a[i], b[j], acc[i][j]);
      }
      if (ct + 8 < 256) {
        *reinterpret_cast<float4*>(&As[buf ^ 1][lr][lc]) = av;
        *reinterpret_cast<float4*>(&Bs[buf ^ 1][lr][lc]) = bv;
      }
    }
  }

  #pragma unroll
  for (int half = 0; half < 2; ++half) {
    #pragma unroll
    for (int i = 0; i < 4; ++i) {
      float* Dp = D + (size_t)(k0 + half * 64 + ty * 4 + i) * ldD + j0;
      *reinterpret_cast<float4*>(Dp + tx * 4)      = *reinterpret_cast<const float4*>(&acc[half * 4 + i][0]);
      *reinterpret_cast<float4*>(Dp + 64 + tx * 4) = *reinterpret_cast<const float4*>(&acc[half * 4 + i][4]);
    }
  }
}

// ---------------- 9-tap DIAGONAL sum + max/argmax, 8 q per thread ----------------
__global__ __launch_bounds__(256) void reduce_max8(const float* __restrict__ Dbase,
                                                   int ldD, int C0, int Q0,
                                                   const float* __restrict__ kinv,
                                                   float* __restrict__ chunkv,
                                                   int* __restrict__ chunki,
                                                   int n0, long long dstride) {
  __shared__ float sk[KCH];
  const int n = n0 + blockIdx.z;
  const float* D = Dbase + (size_t)blockIdx.z * (size_t)dstride;
  const int k0 = blockIdx.y * KCH;
  const int kh = k0 >> 6;
  const int kwb = k0 & 63;
  if (threadIdx.x < KCH) sk[threadIdx.x] = kinv[n * 4096 + k0 + threadIdx.x];
  __syncthreads();

  const int q0 = Q0 + (blockIdx.x * 256 + threadIdx.x) * 8;
  const int qh = q0 >> 6;
  const int qw0 = q0 & 63;
  const bool up = (kh > 0) && (qh > 0);
  const bool dn = (kh < 63) && (qh < 63);
  const bool lf_ok = qw0 > 0;
  const bool rt_ok = qw0 < 56;

  float best[8];
  int bidx[8];
  #pragma unroll
  for (int i = 0; i < 8; ++i) { best[i] = -INFINITY; bidx[i] = k0; }

  const float* Dq = D + (q0 - C0);
  const int step = ldD + 1;

  #pragma unroll 2
  for (int kk = 0; kk < KCH; ++kk) {
    const int kw = kwb + kk;
    const float* P = Dq + (size_t)(k0 + kk) * ldD;
    float r[8];
    {
      float4 c0 = *reinterpret_cast<const float4*>(P);
      float4 c1 = *reinterpret_cast<const float4*>(P + 4);
      r[0] = c0.x; r[1] = c0.y; r[2] = c0.z; r[3] = c0.w;
      r[4] = c1.x; r[5] = c1.y; r[6] = c1.z; r[7] = c1.w;
    }
    if (up) {
      float4 c0 = *reinterpret_cast<const float4*>(P - 64 * step);
      float4 c1 = *reinterpret_cast<const float4*>(P - 64 * step + 4);
      r[0] += c0.x; r[1] += c0.y; r[2] += c0.z; r[3] += c0.w;
      r[4] += c1.x; r[5] += c1.y; r[6] += c1.z; r[7] += c1.w;
    }
    if (dn) {
      float4 c0 = *reinterpret_cast<const float4*>(P + 64 * step);
      float4 c1 = *reinterpret_cast<const float4*>(P + 64 * step + 4);
      r[0] += c0.x; r[1] += c0.y; r[2] += c0.z; r[3] += c0.w;
      r[4] += c1.x; r[5] += c1.y; r[6] += c1.z; r[7] += c1.w;
    }
    if (kw > 0) {
      const float* base = P - step;
      f4u a0 = *reinterpret_cast<const f4u*>(base);
      f4u a1 = *reinterpret_cast<const f4u*>(base + 4);
      r[0] += lf_ok ? a0.v[0] : 0.f; r[1] += a0.v[1]; r[2] += a0.v[2]; r[3] += a0.v[3];
      r[4] += a1.v[0]; r[5] += a1.v[1]; r[6] += a1.v[2]; r[7] += a1.v[3];
      if (up) {
        const float* b = P - 65 * step;
        f4u b0 = *reinterpret_cast<const f4u*>(b);
        f4u b1 = *reinterpret_cast<const f4u*>(b + 4);
        r[0] += lf_ok ? b0.v[0] : 0.f; r[1] += b0.v[1]; r[2] += b0.v[2]; r[3] += b0.v[3];
        r[4] += b1.v[0]; r[5] += b1.v[1]; r[6] += b1.v[2]; r[7] += b1.v[3];
      }
      if (dn) {
        const float* b = P + 63 * step;
        f4u b0 = *reinterpret_cast<const f4u*>(b);
        f4u b1 = *reinterpret_cast<const f4u*>(b + 4);
        r[0] += lf_ok ? b0.v[0] : 0.f; r[1] += b0.v[1]; r[2] += b0.v[2]; r[3] += b0.v[3];
        r[4] += b1.v[0]; r[5] += b1.v[1]; r[6] += b1.v[2]; r[7] += b1.v[3];
      }
    }
    if (kw < 63) {
      const float* base = P + step;
      f4u a0 = *reinterpret_cast<const f4u*>(base);
      f4u a1 = *reinterpret_cast<const f4u*>(base + 4);
      r[0] += a0.v[0]; r[1] += a0.v[1]; r[2] += a0.v[2]; r[3] += a0.v[3];
      r[4] += a1.v[0]; r[5] += a1.v[1]; r[6] += a1.v[2]; r[7] += rt_ok ? a1.v[3] : 0.f;
      if (up) {
        const float* b = P - 63 * step;
        f4u b0 = *reinterpret_cast<const f4u*>(b);
        f4u b1 = *reinterpret_cast<const f4u*>(b + 4);
        r[0] += b0.v[0]; r[1] += b0.v[1]; r[2] += b0.v[2]; r[3] += b0.v[3];
        r[4] += b1.v[0]; r[5] += b1.v[1]; r[6] += b1.v[2]; r[7] += rt_ok ? b1.v[3] : 0.f;
      }
      if (dn) {
        const float* b = P + 65 * step;
        f4u b0 = *reinterpret_cast<const f4u*>(b);
        f4u b1 = *reinterpret_cast<const f4u*>(b + 4);
        r[0] += b0.v[0]; r[1] += b0.v[1]; r[2] += b0.v[2]; r[3] += b0.v[3];
        r[4] += b1.v[0]; r[5] += b1.v[1]; r[6] += b1.v[2]; r[7] += rt_ok ? b1.v[3] : 0.f;
      }
    }
    const float s = sk[kk];
    const int k = k0 + kk;
    #pragma unroll
    for (int i = 0; i < 8; ++i) {
      float v = r[i] * s;
      if (v > best[i]) { best[i] = v; bidx[i] = k; }
    }
  }
  const int ob = (n * KC2 + blockIdx.y) * 4096 + q0;
  *reinterpret_cast<float4*>(chunkv + ob)     = make_float4(best[0], best[1], best[2], best[3]);
  *reinterpret_cast<float4*>(chunkv + ob + 4) = make_float4(best[4], best[5], best[6], best[7]);
  *reinterpret_cast<int4*>(chunki + ob)     = make_int4(bidx[0], bidx[1], bidx[2], bidx[3]);
  *reinterpret_cast<int4*>(chunki + ob + 4) = make_int4(bidx[4], bidx[5], bidx[6], bidx[7]);
}

// ---------------- combine chunks ----------------
__global__ __launch_bounds__(256) void combine_k(const float* __restrict__ chunkv,
                                                 const int* __restrict__ chunki,
                                                 const float* __restrict__ qinv,
                                                 float* __restrict__ out_sa,
                                                 int* __restrict__ maxidx) {
  int t = blockIdx.x * 256 + threadIdx.x;   // 0..8191
  int n = t >> 12, q = t & 4095;
  float best = -INFINITY;
  int bi = 0;
  #pragma unroll 8
  for (int ch = 0; ch < KC2; ++ch) {
    int ii = (n * KC2 + ch) * 4096 + q;
    float v = chunkv[ii];
    int ix = chunki[ii];
    if (v > best) { best = v; bi = ix; }
  }
  maxidx[t] = bi;
  out_sa[t] = best * qinv[t];
}

// ---------------- tex0: LDS-staged gather, 4 channels interleaved ----------------
// grid (64 cquad, 2 n, 2 pxhalf); block 256; LDS 64KB = 4 planes of 16KB
__global__ __launch_bounds__(256) void tex0_lds(const float* __restrict__ ref,
                                                const int* __restrict__ maxidx,
                                                float* __restrict__ outp) {
  __shared__ __align__(16) float4 L[4096];
  const int cq = blockIdx.x;
  const int n  = blockIdx.y;
  const int half = blockIdx.z;
  const int tid = threadIdx.x;
  const float* p0 = ref + (((size_t)n * 256 + cq * 4) << 12);
  for (int i = 0; i < 16; ++i) {
    int px = i * 256 + tid;
    L[px] = make_float4(p0[px], p0[px + 4096], p0[px + 8192], p0[px + 12288]);
  }
  __syncthreads();
  const int* mi = maxidx + n * 4096;
  float* ob = outp + (((size_t)n * 256 + cq * 4) << 12);
  for (int i = 0; i < 8; ++i) {
    int px = half * 2048 + i * 256 + tid;
    int y = px >> 6, x = px & 63;
    float ax = 0.f, ay = 0.f, az = 0.f, aw = 0.f;
    #pragma unroll
    for (int a = -1; a <= 1; ++a) {
      int jh = y + a;
      if ((unsigned)jh < 64u) {
        #pragma unroll
        for (int b = -1; b <= 1; ++b) {
          int jw = x + b;
          if ((unsigned)jw < 64u) {
            int m = mi[jh * 64 + jw];
            int rh = (m >> 6) - a;
            int cx = (m & 63) - b;
            if ((unsigned)rh < 64u && (unsigned)cx < 64u) {
              float4 v = L[rh * 64 + cx];
              ax += v.x; ay += v.y; az += v.z; aw += v.w;
            }
          }
        }
      }
    }
    ob[px]         = ax * (1.f / 9.f);
    ob[px + 4096]  = ay * (1.f / 9.f);
    ob[px + 8192]  = az * (1.f / 9.f);
    ob[px + 12288] = aw * (1.f / 9.f);
  }
}

// ---------------- tex1: LDS-staged gather, one 128x128 plane ----------------
// grid (128 c, 2 n, 2 pairhalf); block 256; LDS 64KB
__global__ __launch_bounds__(256) void tex1_lds(const float* __restrict__ ref,
                                                const int* __restrict__ maxidx,
                                                float* __restrict__ outp) {
  __shared__ __align__(16) float Lf[16384];
  const int c = blockIdx.x;
  const int n = blockIdx.y;
  const int half = blockIdx.z;
  const int tid = threadIdx.x;
  const float* p0 = ref + (((size_t)n * 128 + c) << 14);
  float4* L4 = (float4*)Lf;
  const float4* g4 = (const float4*)p0;
  for (int i = 0; i < 16; ++i) {
    int g = i * 256 + tid;
    L4[g] = g4[g];
  }
  __syncthreads();
  const int* mi = maxidx + n * 4096;
  float* ob = outp + (((size_t)n * 128 + c) << 14);
  // 8192 x-pairs (y in [0,128), xp in [0,64)); half -> 4096; 16 per thread
  for (int i = 0; i < 16; ++i) {
    int pp = half * 4096 + i * 256 + tid;
    int xp = pp & 63;
    int y  = pp >> 6;
    int jh0 = y >> 1;
    float a0 = 0.f, a1 = 0.f;
    #pragma unroll
    for (int a = -1; a <= 1; ++a) {
      int jh = jh0 + a;
      if ((unsigned)jh < 64u) {
        #pragma unroll
        for (int b = -1; b <= 1; ++b) {
          int jw = xp + b;
          if ((unsigned)jw < 64u) {
            int m = mi[jh * 64 + jw];
            int rh = (m >> 6) - a;
            int cx = (m & 63) - b;
            if ((unsigned)rh < 64u && (unsigned)cx < 64u) {
              int off = ((rh << 1) + (y & 1)) * 128 + (cx << 1);
              float2 v = *reinterpret_cast<const float2*>(&Lf[off]);
              a0 += v.x; a1 += v.y;
            }
          }
        }
      }
    }
    *reinterpret_cast<float2*>(&ob[y * 128 + xp * 2]) =
        make_float2(a0 * (1.f / 9.f), a1 * (1.f / 9.f));
  }
}

// ---------------- tex2: global float4 taps (unchanged) ----------------
__global__ __launch_bounds__(256) void tex2_k(const float* __restrict__ ref,
                                              const int* __restrict__ maxidx,
                                              float* __restrict__ outp) {
  int gid = blockIdx.x * 256 + threadIdx.x;   // 262144
  const int xg = gid & 63;
  const int y  = (gid >> 6) & 255;
  const int cc = (gid >> 14) & 7;
  const int n  = gid >> 17;
  const int jh0 = y >> 2;
  const int* mi = maxidx + n * 4096;

  int offs[9];
  #pragma unroll
  for (int a = -1; a <= 1; ++a) {
    #pragma unroll
    for (int b = -1; b <= 1; ++b) {
      const int t = (a + 1) * 3 + (b + 1);
      int jh = jh0 + a, jw = xg + b;
      int off = -1;
      if ((unsigned)jh < 64u && (unsigned)jw < 64u) {
        int m = mi[jh * 64 + jw];
        int rh = (m >> 6) - jh + jh0;
        int cx = (m & 63) - jw + xg;
        if ((unsigned)rh < 64u && (unsigned)cx < 64u)
          off = ((rh << 2) + (y & 3)) * 256 + (cx << 2);
      }
      offs[t] = off;
    }
  }
  const float* rb = ref + (((size_t)n * 64 + cc * 8) << 16);
  float* ob = outp + ((((size_t)n * 64 + cc * 8) * 256 + y) << 8) + xg * 4;
  #pragma unroll
  for (int i = 0; i < 8; ++i) {
    const float* r = rb + ((size_t)i << 16);
    float4 acc = make_float4(0.f, 0.f, 0.f, 0.f);
    #pragma unroll
    for (int t = 0; t < 9; ++t) {
      if (offs[t] >= 0) {
        float4 v = *reinterpret_cast<const float4*>(r + offs[t]);
        acc.x += v.x; acc.y += v.y; acc.z += v.z; acc.w += v.w;
      }
    }
    acc.x *= (1.f / 9.f); acc.y *= (1.f / 9.f); acc.z *= (1.f / 9.f); acc.w *= (1.f / 9.f);
    *reinterpret_cast<float4*>(ob + ((size_t)i << 16)) = acc;
  }
}

// ---------------- launch ----------------
extern "C" void kernel_launch(void* const* d_in, const int* in_sizes, int n_in,
                              void* d_out, int out_size, void* d_ws, size_t ws_size,
                              hipStream_t stream) {
  const float* lq    = (const float*)d_in[0];
  const float* refdu = (const float*)d_in[1];
  const float* ref0  = (const float*)d_in[2];
  const float* ref1  = (const float*)d_in[3];
  const float* ref2  = (const float*)d_in[4];
  float* out = (float*)d_out;

  float* S      = (float*)d_ws;               // 16384
  float* qinv   = S + 16384;                  // 8192
  float* kinv   = qinv + 8192;                // 8192
  int*   maxidx = (int*)(kinv + 8192);        // 8192
  float* chunkv = (float*)(maxidx + 8192);    // 2*KC2*4096 = 1048576
  int*   chunki = (int*)(chunkv + 1048576);   // 1048576
  const size_t aux_bytes = (size_t)(16384 + 8192 + 8192 + 8192 + 1048576 + 1048576) * 4;
  float* D = (float*)((char*)d_ws + aux_bytes);

  size_t avail = (ws_size > aux_bytes) ? (ws_size - aux_bytes) : 0;
  const size_t stripe4096 = (size_t)4096 * 4352 * 4;

  sumsq_k<<<dim3(16, 2, 2), 256, 0, stream>>>(lq, refdu, S);
  norm_k<<<dim3(64), 256, 0, stream>>>(S, qinv, kinv);

  if (avail >= 2 * stripe4096) {
    const int ldD = 4352, C0 = -128;
    const long long dstride = (long long)4096 * 4352;
    gemm_d<<<dim3(32, ldD / 128, 2), 256, 0, stream>>>(refdu, lq, D, ldD, C0, dstride);
    reduce_max8<<<dim3(2, KC2, 2), 256, 0, stream>>>(D, ldD, C0, 0, kinv,
                                                     chunkv, chunki, 0, dstride);
  } else {
    int Wq = 2048;
    if ((size_t)4096 * (4096 + 256) * 4 <= avail) Wq = 4096;
    const int ldD = Wq + 256;
    for (int n = 0; n < 2; ++n) {
      const float* A = refdu + (size_t)n * 1048576;
      const float* B = lq    + (size_t)n * 1048576;
      for (int Q0 = 0; Q0 < 4096; Q0 += Wq) {
        int C0 = Q0 - 128;
        gemm_d<<<dim3(32, ldD / 128, 1), 256, 0, stream>>>(A, B, D, ldD, C0, 0);
        reduce_max8<<<dim3(Wq / 2048, KC2, 1), 256, 0, stream>>>(
            D, ldD, C0, Q0, kinv, chunkv, chunki, n, 0);
      }
    }
  }

  combine_k<<<dim3(32), 256, 0, stream>>>(chunkv, chunki, qinv, out, maxidx);

  tex0_lds<<<dim3(64, 2, 2),  256, 0, stream>>>(ref0, maxidx, out + 8192);
  tex1_lds<<<dim3(128, 2, 2), 256, 0, stream>>>(ref1, maxidx, out + 2105344);
  tex2_k<<<dim3(1024), 256, 0, stream>>>(ref2, maxidx, out + 6299648);
}